// Round 7
// baseline (316.937 us; speedup 1.0000x reference)
//
#include <hip/hip_runtime.h>

#define B_    8192
#define T_    256
#define F_    18
#define U_    32
#define NIDS  1000
#define NPROD 256      // producer blocks (one per t)
#define NCONS 250      // consumer blocks (4 chains each)

typedef float v2f  __attribute__((ext_vector_type(2)));
typedef float vf4  __attribute__((ext_vector_type(4)));
typedef v2f  f2a   __attribute__((may_alias));
typedef vf4  f4a   __attribute__((may_alias));
typedef float uf4  __attribute__((ext_vector_type(4), aligned(4), may_alias));
typedef float uf2  __attribute__((ext_vector_type(2), aligned(4), may_alias));

#define V2LO(v) __builtin_shufflevector(v, v, 0, 1)
#define V2HI(v) __builtin_shufflevector(v, v, 2, 3)

__device__ __forceinline__ float hsig(float x) {
    return fminf(fmaxf(fmaf(x, 0.2f, 0.5f), 0.f), 1.f);
}
__device__ __forceinline__ float ftanh(float x) {
    float g = __builtin_amdgcn_exp2f(2.885390081777927f * x);
    return 1.f - 2.f * __builtin_amdgcn_rcpf(g + 1.f);
}

// ---------------------------------------------------------------------------
// One GRU step (unchanged from R5): h and p broadcast through LDS (same-wave
// DS ops are in-order -> no barriers). x-row + validity sentinel come from the
// chunked LDS buffer; next step's x-dots computed in the p round-trip shadow.
// Sentinel: vm=1e6 added to dz -> z==1 -> h_new == h (skipped step).
// ---------------------------------------------------------------------------
__device__ __forceinline__ float do_step(
    const f4a* __restrict__ hb4, const f4a* __restrict__ pb4,
    float* __restrict__ pslot, float* __restrict__ hslot,
    float hown, float& dz, float& dr, float& dh,
    const v2f (&Uz)[16], const v2f (&Ur)[16], const v2f (&Uh)[16],
    const float* __restrict__ xnext,
    const v2f (&Kz)[9], const v2f (&Kr)[9], const v2f (&Kh)[9],
    float bz, float br, float bh)
{
    const float dhc = dh;
    v2f az0 = {dz, 0.f}, az1 = {0.f, 0.f};
    v2f ar0 = {dr, 0.f}, ar1 = {0.f, 0.f};
#pragma unroll
    for (int k = 0; k < 8; ++k) {
        vf4 hv = hb4[k];
        v2f lo = V2LO(hv), hi = V2HI(hv);
        az0 += lo * Uz[2*k];  az1 += hi * Uz[2*k+1];
        ar0 += lo * Ur[2*k];  ar1 += hi * Ur[2*k+1];
    }
    float z = hsig(az0.x + az0.y + az1.x + az1.y);
    float r = hsig(ar0.x + ar0.y + ar1.x + ar1.y);
    *pslot = r * hown;                       // ds_write p_j

    // filler while p write->read round-trips: next step's x-dots from LDS
    const f4a* xp = (const f4a*)xnext;
    vf4 x0 = xp[0], x1 = xp[1], x2 = xp[2], x3 = xp[3];
    v2f x4 = *(const f2a*)(xnext + 16);
    float vm = xnext[18];
    v2f nz = {bz, 0.f}, nr = {br, 0.f}, nh = {bh, 0.f};
    v2f xq[9] = {V2LO(x0), V2HI(x0), V2LO(x1), V2HI(x1),
                 V2LO(x2), V2HI(x2), V2LO(x3), V2HI(x3), x4};
#pragma unroll
    for (int q = 0; q < 9; ++q) {
        nz += xq[q] * Kz[q]; nr += xq[q] * Kr[q]; nh += xq[q] * Kh[q];
    }
    dz = nz.x + nz.y + vm; dr = nr.x + nr.y; dh = nh.x + nh.y;

    v2f ah0 = {dhc, 0.f}, ah1 = {0.f, 0.f};
#pragma unroll
    for (int k = 0; k < 8; ++k) {
        vf4 pv = pb4[k];
        ah0 += V2LO(pv) * Uh[2*k];  ah1 += V2HI(pv) * Uh[2*k+1];
    }
    float hh = ftanh(ah0.x + ah0.y + ah1.x + ah1.y);
    float hn = fmaf(z, hown - hh, hh);
    *hslot = hn;                             // ds_write h_j for next step
    return hn;
}

// ---------------------------------------------------------------------------
// Fused producer/consumer kernel.
//   blocks [0,256):  producer for t=blockIdx — gather ids, LDS atomicMax,
//                    write winner column, fence, release flag[t].
//   blocks [256,506): consumer — 2 waves x 2 chains (R5's proven regime),
//                    winner reads chunked, gated by early-probed flags.
// Capacity: 506 blocks, <=256 VGPR, ~11KB LDS -> all co-resident (no deadlock).
// ---------------------------------------------------------------------------
struct ConsSh {
    float xbuf[2][2][2][16][20];   // [wave][buf][chain][row][18x + vm + pad]
    float pbuf[2][2][32];
    float hbuf[2][2][32];
};
struct ProdSh { int loc[NIDS]; };
union SmemU { ConsSh c; ProdSh p; };

__global__ __launch_bounds__(128, 2) void fused_chains(
    const float* __restrict__ inputs, const float* __restrict__ K,
    const float* __restrict__ R, const float* __restrict__ bias,
    const float* __restrict__ sinit, int* __restrict__ winner,
    int* __restrict__ flags, float* __restrict__ table)
{
    __shared__ SmemU sh;

    if (blockIdx.x < NPROD) {
        // ---------------- producer ----------------
        const int t = blockIdx.x;
        const int tid = threadIdx.x;
        int* loc = sh.p.loc;
        for (int i = tid; i < NIDS; i += 128) loc[i] = -1;
        __syncthreads();
        int ids[64];
#pragma unroll
        for (int u = 0; u < 64; ++u) {
            int b = u * 128 + tid;
            ids[u] = (int)inputs[((size_t)b * T_ + t) * F_];
        }
#pragma unroll
        for (int u = 0; u < 64; ++u) {
            int id = ids[u];
            id = id < 0 ? 0 : (id > NIDS - 1 ? NIDS - 1 : id);
            atomicMax(&loc[id], u * 128 + tid);
        }
        __syncthreads();
        for (int i = tid; i < NIDS; i += 128) winner[t * NIDS + i] = loc[i];
        __threadfence();
        __syncthreads();
        if (tid == 0)
            __hip_atomic_store(&flags[t], 1, __ATOMIC_RELEASE, __HIP_MEMORY_SCOPE_AGENT);
        return;
    }

    // ---------------- consumer ----------------
    const int cblk = blockIdx.x - NPROD;
    const int wv = threadIdx.x >> 6;         // 0..1
    const int lane = threadIdx.x & 63;
    const int c = lane >> 5, j = lane & 31;
    const int chain0 = cblk * 4 + wv * 2;    // this wave's first chain
    const int chain = chain0 + c;

    v2f Uz[16], Ur[16], Uh[16];
#pragma unroll
    for (int k = 0; k < 16; ++k) {
        Uz[k] = (v2f){R[(2*k)*96 + j],      R[(2*k+1)*96 + j]};
        Ur[k] = (v2f){R[(2*k)*96 + 32 + j], R[(2*k+1)*96 + 32 + j]};
        Uh[k] = (v2f){R[(2*k)*96 + 64 + j], R[(2*k+1)*96 + 64 + j]};
    }
    v2f Kz[9], Kr[9], Kh[9];
#pragma unroll
    for (int q = 0; q < 9; ++q) {
        Kz[q] = (v2f){K[(2*q)*96 + j],      K[(2*q+1)*96 + j]};
        Kr[q] = (v2f){K[(2*q)*96 + 32 + j], K[(2*q+1)*96 + 32 + j]};
        Kh[q] = (v2f){K[(2*q)*96 + 64 + j], K[(2*q+1)*96 + 64 + j]};
    }
    const float bz = bias[j], br = bias[32 + j], bh = bias[64 + j];

    float hinit = sinit[chain * U_ + j];
    sh.c.hbuf[wv][c][j] = hinit;
    float hown = hinit;

    // staging role: 2 lanes per row; 32 rows = 2 chains x 16 steps
    const int rr = lane >> 1, pp = lane & 1;
    const int scc = rr >> 4, sidx = rr & 15;

    uf4 r0, r1; uf2 r2; float vmk = 0.f;

    auto wait_chunk = [&](int ck) {
        const int* fp = flags + ck * 16 + (lane & 15);
        while (__hip_atomic_load(fp, __ATOMIC_RELAXED, __HIP_MEMORY_SCOPE_AGENT) == 0)
            __builtin_amdgcn_s_sleep(4);
        __threadfence();   // acquire: winner data visible after flags seen
    };
    auto issue_loads = [&](int ck) {
        int tt = ck * 16 + sidx;
        int w = (tt < T_ - 1) ? winner[tt * NIDS + chain0 + scc] : -1;
        vmk = (w < 0) ? 1e6f : 0.f;
        int wc = w < 0 ? 0 : w;
        const float* src = inputs + (size_t)(wc * T_ + tt) * F_;
        if (pp == 0) { r0 = *(const uf4*)(src);      r1 = *(const uf4*)(src + 4); }
        else         { r0 = *(const uf4*)(src + 8);  r1 = *(const uf4*)(src + 12);
                       r2 = *(const uf2*)(src + 16); }
    };
    auto write_buf = [&](int nb) {
        float* dst = &sh.c.xbuf[wv][nb][scc][sidx][0];
        if (pp == 0) { *(f4a*)(dst)      = (vf4)r0; *(f4a*)(dst + 4)  = (vf4)r1; }
        else         { *(f4a*)(dst + 8)  = (vf4)r0; *(f4a*)(dst + 12) = (vf4)r1;
                       *(f2a*)(dst + 16) = (v2f)r2; dst[18] = vmk; }
    };

    // prologue: chunk0 -> buf0; chunk1 loads left in flight
    wait_chunk(0);
    issue_loads(0);
    write_buf(0);
    wait_chunk(1);
    issue_loads(1);

    // initial dots for t=0 from buf0 row0
    float dz, dr, dh;
    {
        const float* x = &sh.c.xbuf[wv][0][c][0][0];
        const f4a* xp = (const f4a*)x;
        vf4 x0 = xp[0], x1 = xp[1], x2 = xp[2], x3 = xp[3];
        v2f x4 = *(const f2a*)(x + 16);
        float vm = x[18];
        v2f xq[9] = {V2LO(x0), V2HI(x0), V2LO(x1), V2HI(x1),
                     V2LO(x2), V2HI(x2), V2LO(x3), V2HI(x3), x4};
        v2f nz = {bz, 0.f}, nr = {br, 0.f}, nh = {bh, 0.f};
#pragma unroll
        for (int q = 0; q < 9; ++q) {
            nz += xq[q] * Kz[q]; nr += xq[q] * Kr[q]; nh += xq[q] * Kh[q];
        }
        dz = nz.x + nz.y + vm; dr = nr.x + nr.y; dh = nh.x + nh.y;
    }

    const f4a* hb4 = (const f4a*)sh.c.hbuf[wv][c];
    const f4a* pb4 = (const f4a*)sh.c.pbuf[wv][c];
    float* pslot = &sh.c.pbuf[wv][c][j];
    float* hslot = &sh.c.hbuf[wv][c][j];

    for (int i = 0; i < 16; ++i) {
        // early non-blocking probe of chunk i+2's flags; checked after steps
        int pf = 1;
        if (i < 14)
            pf = __hip_atomic_load(&flags[(i + 2) * 16 + (lane & 15)],
                                   __ATOMIC_RELAXED, __HIP_MEMORY_SCOPE_AGENT);

        const float* bufc  = &sh.c.xbuf[wv][i & 1][c][0][0];
        const float* nbufc = &sh.c.xbuf[wv][(i + 1) & 1][c][0][0];
        for (int s = 0; s < 15; ++s) {
            hown = do_step(hb4, pb4, pslot, hslot, hown, dz, dr, dh,
                           Uz, Ur, Uh, bufc + (s + 1) * 20,
                           Kz, Kr, Kh, bz, br, bh);
        }
        if (i < 15) {
            write_buf((i + 1) & 1);
            if (i < 14) {
                if (__all(pf != 0)) __threadfence();
                else                wait_chunk(i + 2);
                issue_loads(i + 2);
            }
        }
        hown = do_step(hb4, pb4, pslot, hslot, hown, dz, dr, dh,
                       Uz, Ur, Uh, nbufc,
                       Kz, Kr, Kh, bz, br, bh);
    }

    table[chain * U_ + j] = hown;            // state entering t=255
}

// ---------------------------------------------------------------------------
// Phase 3: final step t=255 for all 8192 batch elements + MLP + sigmoid.
// ---------------------------------------------------------------------------
__device__ __forceinline__ float fin_gru_step(
    const float (&h)[16], float hown, const float (&xv)[9],
    const float (&Wz)[16], const float (&Wr)[16], const float (&Wh)[16],
    const float (&Kz)[9],  const float (&Kr)[9],  const float (&Kh)[9],
    float bz, float br, float bh, int kh)
{
    float az = 0.f, ar = 0.f;
#pragma unroll
    for (int kk = 0; kk < 16; ++kk) {
        az = fmaf(h[kk], Wz[kk], az);
        ar = fmaf(h[kk], Wr[kk], ar);
    }
#pragma unroll
    for (int q = 0; q < 9; ++q) {
        az = fmaf(xv[q], Kz[q], az);
        ar = fmaf(xv[q], Kr[q], ar);
    }
    az += __shfl_xor(az, 32, 64);
    ar += __shfl_xor(ar, 32, 64);
    float z = hsig(az + bz);
    float r = hsig(ar + br);
    float p = r * hown;
    float ah = 0.f;
#pragma unroll
    for (int kk = 0; kk < 16; ++kk) {
        float pkv = __shfl(p, kh * 16 + kk, 64);
        ah = fmaf(pkv, Wh[kk], ah);
    }
#pragma unroll
    for (int q = 0; q < 9; ++q) ah = fmaf(xv[q], Kh[q], ah);
    ah += __shfl_xor(ah, 32, 64);
    float hh = tanhf(ah + bh);
    return z * hown + (1.f - z) * hh;
}

__global__ __launch_bounds__(256) void finalize(
    const float* __restrict__ inputs, const float* __restrict__ K,
    const float* __restrict__ R, const float* __restrict__ bias,
    const float* __restrict__ table, const float* __restrict__ w1,
    const float* __restrict__ b1, const float* __restrict__ w2,
    const float* __restrict__ b2, float* __restrict__ out)
{
    int tid = threadIdx.x;
    int wv = tid >> 6, lane = tid & 63;
    int j = lane & 31, kh = lane >> 5;

    float Wz[16], Wr[16], Wh[16], w1c[16];
#pragma unroll
    for (int kk = 0; kk < 16; ++kk) {
        int k = kh * 16 + kk;
        Wz[kk]  = R[k * 96 + j];
        Wr[kk]  = R[k * 96 + 32 + j];
        Wh[kk]  = R[k * 96 + 64 + j];
        w1c[kk] = w1[k * 32 + j];
    }
    float Kz[9], Kr[9], Kh[9];
#pragma unroll
    for (int q = 0; q < 9; ++q) {
        int k = kh * 9 + q;
        Kz[q] = K[k * 96 + j];
        Kr[q] = K[k * 96 + 32 + j];
        Kh[q] = K[k * 96 + 64 + j];
    }
    float bz = bias[j], br = bias[32 + j], bh = bias[64 + j];
    float b1v = b1[j], w2v = w2[j], b2v = b2[0];

    int b0 = (blockIdx.x * 4 + wv) * 8;
    for (int bb = 0; bb < 8; ++bb) {
        int b = b0 + bb;
        const float* row = inputs + ((size_t)b * T_ + (T_ - 1)) * F_;
        int id = (int)row[0];
        float xv[9];
#pragma unroll
        for (int q = 0; q < 9; ++q) xv[q] = row[kh * 9 + q];
        float h[16], hown;
#pragma unroll
        for (int kk = 0; kk < 16; ++kk) h[kk] = table[id * U_ + kh * 16 + kk];
        hown = table[id * U_ + j];

        float hn = fin_gru_step(h, hown, xv, Wz, Wr, Wh, Kz, Kr, Kh, bz, br, bh, kh);
        float hrep[16];
#pragma unroll
        for (int kk = 0; kk < 16; ++kk) hrep[kk] = __shfl(hn, kh * 16 + kk, 64);

        float am = 0.f;
#pragma unroll
        for (int kk = 0; kk < 16; ++kk) am = fmaf(hrep[kk], w1c[kk], am);
        am += __shfl_xor(am, 32, 64);
        float hid = fmaxf(am + b1v, 0.f);
        float pr = (kh == 0) ? hid * w2v : 0.f;
#pragma unroll
        for (int s = 1; s < 64; s <<= 1) pr += __shfl_xor(pr, s, 64);
        if (lane == 0) out[b] = 1.f / (1.f + expf(-(pr + b2v)));
    }
}

// ---------------------------------------------------------------------------
extern "C" void kernel_launch(void* const* d_in, const int* in_sizes, int n_in,
                              void* d_out, int out_size, void* d_ws, size_t ws_size,
                              hipStream_t stream)
{
    const float* inputs = (const float*)d_in[0];
    const float* K      = (const float*)d_in[1];
    const float* R      = (const float*)d_in[2];
    const float* bias   = (const float*)d_in[3];
    const float* sinit  = (const float*)d_in[4];
    const float* w1     = (const float*)d_in[5];
    const float* b1     = (const float*)d_in[6];
    const float* w2     = (const float*)d_in[7];
    const float* b2     = (const float*)d_in[8];
    float* out = (float*)d_out;

    int*   winner = (int*)d_ws;                                   // 1.0 MB
    float* table  = (float*)((char*)d_ws + (1 << 20));            // 128 KB
    int*   flags  = (int*)((char*)d_ws + (1 << 20) + (256 << 10)); // 1 KB

    hipMemsetAsync(flags, 0, NPROD * sizeof(int), stream);
    fused_chains<<<dim3(NPROD + NCONS), dim3(128), 0, stream>>>(
        inputs, K, R, bias, sinit, winner, flags, table);
    finalize<<<dim3(B_ / 32), dim3(256), 0, stream>>>(
        inputs, K, R, bias, table, w1, b1, w2, b2, out);
}

// Round 8
// 106.017 us; speedup vs baseline: 2.9895x; 2.9895x over previous
//
#include <hip/hip_runtime.h>

#define B_   8192
#define T_   256
#define F_   18
#define U_   32
#define NIDS 1000

typedef float v2f  __attribute__((ext_vector_type(2)));
typedef float vf4  __attribute__((ext_vector_type(4)));
typedef v2f  f2a   __attribute__((may_alias));
typedef vf4  f4a   __attribute__((may_alias));
typedef float uf4  __attribute__((ext_vector_type(4), aligned(4), may_alias));
typedef float uf2  __attribute__((ext_vector_type(2), aligned(4), may_alias));

#define V2LO(v) __builtin_shufflevector(v, v, 0, 1)
#define V2HI(v) __builtin_shufflevector(v, v, 2, 3)

__device__ __forceinline__ float hsig(float x) {
    return fminf(fmaxf(fmaf(x, 0.2f, 0.5f), 0.f), 1.f);
}
__device__ __forceinline__ float ftanh(float x) {
    float g = __builtin_amdgcn_exp2f(2.885390081777927f * x);
    return 1.f - 2.f * __builtin_amdgcn_rcpf(g + 1.f);
}

// ---------------------------------------------------------------------------
// Phase 1a: coalesced float4 stream; extract ids, stage in LDS tile, write
// transposed compact u16 id array ids_t[t][8192]. No atomics.
// ---------------------------------------------------------------------------
__global__ __launch_bounds__(1024) void extract_ids(
    const float4* __restrict__ in4, unsigned short* __restrict__ ids_t)
{
    __shared__ unsigned short tile[256][32];     // [t][b_local], 16 KB
    const int tid = threadIdx.x;
    const int blk = blockIdx.x;
    const int base = blk * 36864;                // 32 rows * 256 t * 18 / 4
#pragma unroll 9
    for (int k = 0; k < 36; ++k) {
        int v = k * 1024 + tid;
        float4 f = in4[base + v];
        unsigned e0 = (unsigned)v * 4u;
        unsigned rem = e0 % 18u;
        int j = (rem == 0u) ? 0 : (rem == 16u ? 2 : -1);
        if (j >= 0) {
            float fv = (j == 0) ? f.x : f.z;
            unsigned m = (e0 + (unsigned)j) / 18u;   // local ordinal: b_l*256+t
            int t = (int)(m & 255u);
            int bl = (int)(m >> 8);
            int id = (int)fv;
            id = id < 0 ? 0 : (id > NIDS - 1 ? NIDS - 1 : id);
            tile[t][bl] = (unsigned short)id;
        }
    }
    __syncthreads();
    const unsigned* tl = (const unsigned*)tile;  // index i = t*16 + p (2 ids)
    unsigned* dst = (unsigned*)ids_t;
#pragma unroll
    for (int i = tid; i < 4096; i += 1024) {
        int t = i >> 4, p = i & 15;
        dst[t * 4096 + blk * 16 + p] = tl[i];
    }
}

// ---------------------------------------------------------------------------
// Phase 1b: block per t; contiguous 16KB id column, LDS atomicMax, write
// winner column (every entry written -> no memset).
// ---------------------------------------------------------------------------
__global__ __launch_bounds__(1024) void find_winners(
    const unsigned short* __restrict__ ids_t, int* __restrict__ winner)
{
    __shared__ int loc[NIDS];
    const int tid = threadIdx.x;
    const int t = blockIdx.x;
    for (int i = tid; i < NIDS; i += 1024) loc[i] = -1;
    __syncthreads();

    uint4 v = ((const uint4*)(ids_t + t * 8192))[tid];   // 8 ids, b=tid*8+e
    int b0 = tid * 8;
    atomicMax(&loc[v.x & 0xFFFFu], b0 + 0);
    atomicMax(&loc[v.x >> 16],     b0 + 1);
    atomicMax(&loc[v.y & 0xFFFFu], b0 + 2);
    atomicMax(&loc[v.y >> 16],     b0 + 3);
    atomicMax(&loc[v.z & 0xFFFFu], b0 + 4);
    atomicMax(&loc[v.z >> 16],     b0 + 5);
    atomicMax(&loc[v.w & 0xFFFFu], b0 + 6);
    atomicMax(&loc[v.w >> 16],     b0 + 7);
    __syncthreads();
    for (int i = tid; i < NIDS; i += 1024) winner[t * NIDS + i] = loc[i];
}

// ---------------------------------------------------------------------------
// Phase 2: one GRU step (LDS broadcast, sentinel validity).
// ---------------------------------------------------------------------------
__device__ __forceinline__ float do_step(
    const f4a* __restrict__ hb4, const f4a* __restrict__ pb4,
    float* __restrict__ pslot, float* __restrict__ hslot,
    float hown, float& dz, float& dr, float& dh,
    const v2f (&Uz)[16], const v2f (&Ur)[16], const v2f (&Uh)[16],
    const float* __restrict__ xnext,
    const v2f (&Kz)[9], const v2f (&Kr)[9], const v2f (&Kh)[9],
    float bz, float br, float bh)
{
    const float dhc = dh;
    v2f az0 = {dz, 0.f}, az1 = {0.f, 0.f};
    v2f ar0 = {dr, 0.f}, ar1 = {0.f, 0.f};
#pragma unroll
    for (int k = 0; k < 8; ++k) {
        vf4 hv = hb4[k];
        v2f lo = V2LO(hv), hi = V2HI(hv);
        az0 += lo * Uz[2*k];  az1 += hi * Uz[2*k+1];
        ar0 += lo * Ur[2*k];  ar1 += hi * Ur[2*k+1];
    }
    float z = hsig(az0.x + az0.y + az1.x + az1.y);
    float r = hsig(ar0.x + ar0.y + ar1.x + ar1.y);
    *pslot = r * hown;                       // ds_write p_j

    // filler while p write->read round-trips: next step's x-dots from LDS
    const f4a* xp = (const f4a*)xnext;
    vf4 x0 = xp[0], x1 = xp[1], x2 = xp[2], x3 = xp[3];
    v2f x4 = *(const f2a*)(xnext + 16);
    float vm = xnext[18];
    v2f nz = {bz, 0.f}, nr = {br, 0.f}, nh = {bh, 0.f};
    v2f xq[9] = {V2LO(x0), V2HI(x0), V2LO(x1), V2HI(x1),
                 V2LO(x2), V2HI(x2), V2LO(x3), V2HI(x3), x4};
#pragma unroll
    for (int q = 0; q < 9; ++q) {
        nz += xq[q] * Kz[q]; nr += xq[q] * Kr[q]; nh += xq[q] * Kh[q];
    }
    dz = nz.x + nz.y + vm; dr = nr.x + nr.y; dh = nh.x + nh.y;

    v2f ah0 = {dhc, 0.f}, ah1 = {0.f, 0.f};
#pragma unroll
    for (int k = 0; k < 8; ++k) {
        vf4 pv = pb4[k];
        ah0 += V2LO(pv) * Uh[2*k];  ah1 += V2HI(pv) * Uh[2*k+1];
    }
    float hh = ftanh(ah0.x + ah0.y + ah1.x + ah1.y);
    float hn = fmaf(z, hown - hh, hh);
    *hslot = hn;                             // ds_write h_j for next step
    return hn;
}

// ---------------------------------------------------------------------------
// Phase 2: 1000 chains, 2/wave, 1 wave/block, 500 blocks (~2 waves/CU).
// 16 chunks x 16 steps; X-rows staged chunk-wise into LDS, double-buffered.
// ---------------------------------------------------------------------------
__global__ __launch_bounds__(64, 1) void run_chains(
    const float* __restrict__ inputs, const float* __restrict__ K,
    const float* __restrict__ R, const float* __restrict__ bias,
    const float* __restrict__ sinit, const int* __restrict__ winner,
    float* __restrict__ table)
{
    __shared__ int wlds[2][256];
    __shared__ alignas(16) float xbuf[2][2][16][20];  // [buf][chain][row][18x+vm+pad]
    __shared__ alignas(16) float pbuf[2][32];
    __shared__ alignas(16) float hbuf[2][32];

    const int lane = threadIdx.x;
    const int c = lane >> 5, j = lane & 31;
    const int chain = blockIdx.x * 2 + c;

    // winner columns -> LDS (single wave: in-order DS, no barrier)
#pragma unroll
    for (int i = 0; i < 8; ++i) {
        int idx = i * 64 + lane;
        int cc = idx >> 8, t = idx & 255;
        wlds[cc][t] = (t < T_ - 1) ? winner[t * NIDS + blockIdx.x * 2 + cc] : -1;
    }
    float hinit = sinit[chain * U_ + j];
    hbuf[c][j] = hinit;
    float hown = hinit;

    v2f Uz[16], Ur[16], Uh[16];
#pragma unroll
    for (int k = 0; k < 16; ++k) {
        Uz[k] = (v2f){R[(2*k)*96 + j],      R[(2*k+1)*96 + j]};
        Ur[k] = (v2f){R[(2*k)*96 + 32 + j], R[(2*k+1)*96 + 32 + j]};
        Uh[k] = (v2f){R[(2*k)*96 + 64 + j], R[(2*k+1)*96 + 64 + j]};
    }
    v2f Kz[9], Kr[9], Kh[9];
#pragma unroll
    for (int q = 0; q < 9; ++q) {
        Kz[q] = (v2f){K[(2*q)*96 + j],      K[(2*q+1)*96 + j]};
        Kr[q] = (v2f){K[(2*q)*96 + 32 + j], K[(2*q+1)*96 + 32 + j]};
        Kh[q] = (v2f){K[(2*q)*96 + 64 + j], K[(2*q+1)*96 + 64 + j]};
    }
    const float bz = bias[j], br = bias[32 + j], bh = bias[64 + j];

    // staging role: 2 lanes per row; 32 rows = 2 chains x 16 steps
    const int rr = lane >> 1, pp = lane & 1;
    const int scc = rr >> 4, sidx = rr & 15;

    uf4 r0, r1; uf2 r2; float vmk = 0.f;

    auto issue_loads = [&](int ck) {
        int tt = ck * 16 + sidx;
        int w = wlds[scc][tt];
        vmk = (w < 0) ? 1e6f : 0.f;
        int wc = w < 0 ? 0 : w;
        const float* src = inputs + (size_t)(wc * 256 + tt) * 18;
        if (pp == 0) { r0 = *(const uf4*)(src);      r1 = *(const uf4*)(src + 4); }
        else         { r0 = *(const uf4*)(src + 8);  r1 = *(const uf4*)(src + 12);
                       r2 = *(const uf2*)(src + 16); }
    };
    auto write_buf = [&](int nb) {
        float* dst = &xbuf[nb][scc][sidx][0];
        if (pp == 0) { *(f4a*)(dst)      = (vf4)r0; *(f4a*)(dst + 4)  = (vf4)r1; }
        else         { *(f4a*)(dst + 8)  = (vf4)r0; *(f4a*)(dst + 12) = (vf4)r1;
                       *(f2a*)(dst + 16) = (v2f)r2; dst[18] = vmk; }
    };

    // prologue: chunk0 -> buf0; chunk1 loads left in flight
    issue_loads(0);
    write_buf(0);
    issue_loads(1);

    // initial dots for t=0 from buf0 row0
    float dz, dr, dh;
    {
        const float* x = &xbuf[0][c][0][0];
        const f4a* xp = (const f4a*)x;
        vf4 x0 = xp[0], x1 = xp[1], x2 = xp[2], x3 = xp[3];
        v2f x4 = *(const f2a*)(x + 16);
        float vm = x[18];
        v2f xq[9] = {V2LO(x0), V2HI(x0), V2LO(x1), V2HI(x1),
                     V2LO(x2), V2HI(x2), V2LO(x3), V2HI(x3), x4};
        v2f nz = {bz, 0.f}, nr = {br, 0.f}, nh = {bh, 0.f};
#pragma unroll
        for (int q = 0; q < 9; ++q) {
            nz += xq[q] * Kz[q]; nr += xq[q] * Kr[q]; nh += xq[q] * Kh[q];
        }
        dz = nz.x + nz.y + vm; dr = nr.x + nr.y; dh = nh.x + nh.y;
    }

    const f4a* hb4 = (const f4a*)hbuf[c];
    const f4a* pb4 = (const f4a*)pbuf[c];
    float* pslot = &pbuf[c][j];
    float* hslot = &hbuf[c][j];

    for (int i = 0; i < 16; ++i) {
        const float* bufc  = &xbuf[i & 1][c][0][0];
        const float* nbufc = &xbuf[(i + 1) & 1][c][0][0];
        for (int s = 0; s < 15; ++s) {
            hown = do_step(hb4, pb4, pslot, hslot, hown, dz, dr, dh,
                           Uz, Ur, Uh, bufc + (s + 1) * 20,
                           Kz, Kr, Kh, bz, br, bh);
        }
        if (i < 15) {
            write_buf((i + 1) & 1);
            if (i < 14) issue_loads(i + 2);
        }
        hown = do_step(hb4, pb4, pslot, hslot, hown, dz, dr, dh,
                       Uz, Ur, Uh, nbufc,
                       Kz, Kr, Kh, bz, br, bh);
    }

    table[chain * U_ + j] = hown;            // state entering t=255
}

// ---------------------------------------------------------------------------
// Phase 3: final step t=255 for all 8192 batch elements + MLP + sigmoid.
// ---------------------------------------------------------------------------
__device__ __forceinline__ float fin_gru_step(
    const float (&h)[16], float hown, const float (&xv)[9],
    const float (&Wz)[16], const float (&Wr)[16], const float (&Wh)[16],
    const float (&Kz)[9],  const float (&Kr)[9],  const float (&Kh)[9],
    float bz, float br, float bh, int kh)
{
    float az = 0.f, ar = 0.f;
#pragma unroll
    for (int kk = 0; kk < 16; ++kk) {
        az = fmaf(h[kk], Wz[kk], az);
        ar = fmaf(h[kk], Wr[kk], ar);
    }
#pragma unroll
    for (int q = 0; q < 9; ++q) {
        az = fmaf(xv[q], Kz[q], az);
        ar = fmaf(xv[q], Kr[q], ar);
    }
    az += __shfl_xor(az, 32, 64);
    ar += __shfl_xor(ar, 32, 64);
    float z = hsig(az + bz);
    float r = hsig(ar + br);
    float p = r * hown;
    float ah = 0.f;
#pragma unroll
    for (int kk = 0; kk < 16; ++kk) {
        float pkv = __shfl(p, kh * 16 + kk, 64);
        ah = fmaf(pkv, Wh[kk], ah);
    }
#pragma unroll
    for (int q = 0; q < 9; ++q) ah = fmaf(xv[q], Kh[q], ah);
    ah += __shfl_xor(ah, 32, 64);
    float hh = tanhf(ah + bh);
    return z * hown + (1.f - z) * hh;
}

__global__ __launch_bounds__(256) void finalize(
    const float* __restrict__ inputs, const float* __restrict__ K,
    const float* __restrict__ R, const float* __restrict__ bias,
    const float* __restrict__ table, const float* __restrict__ w1,
    const float* __restrict__ b1, const float* __restrict__ w2,
    const float* __restrict__ b2, float* __restrict__ out)
{
    int tid = threadIdx.x;
    int wv = tid >> 6, lane = tid & 63;
    int j = lane & 31, kh = lane >> 5;

    float Wz[16], Wr[16], Wh[16], w1c[16];
#pragma unroll
    for (int kk = 0; kk < 16; ++kk) {
        int k = kh * 16 + kk;
        Wz[kk]  = R[k * 96 + j];
        Wr[kk]  = R[k * 96 + 32 + j];
        Wh[kk]  = R[k * 96 + 64 + j];
        w1c[kk] = w1[k * 32 + j];
    }
    float Kz[9], Kr[9], Kh[9];
#pragma unroll
    for (int q = 0; q < 9; ++q) {
        int k = kh * 9 + q;
        Kz[q] = K[k * 96 + j];
        Kr[q] = K[k * 96 + 32 + j];
        Kh[q] = K[k * 96 + 64 + j];
    }
    float bz = bias[j], br = bias[32 + j], bh = bias[64 + j];
    float b1v = b1[j], w2v = w2[j], b2v = b2[0];

    int b0 = (blockIdx.x * 4 + wv) * 8;
    for (int bb = 0; bb < 8; ++bb) {
        int b = b0 + bb;
        const float* row = inputs + ((size_t)b * T_ + (T_ - 1)) * F_;
        int id = (int)row[0];
        float xv[9];
#pragma unroll
        for (int q = 0; q < 9; ++q) xv[q] = row[kh * 9 + q];
        float h[16], hown;
#pragma unroll
        for (int kk = 0; kk < 16; ++kk) h[kk] = table[id * U_ + kh * 16 + kk];
        hown = table[id * U_ + j];

        float hn = fin_gru_step(h, hown, xv, Wz, Wr, Wh, Kz, Kr, Kh, bz, br, bh, kh);
        float hrep[16];
#pragma unroll
        for (int kk = 0; kk < 16; ++kk) hrep[kk] = __shfl(hn, kh * 16 + kk, 64);

        float am = 0.f;
#pragma unroll
        for (int kk = 0; kk < 16; ++kk) am = fmaf(hrep[kk], w1c[kk], am);
        am += __shfl_xor(am, 32, 64);
        float hid = fmaxf(am + b1v, 0.f);
        float pr = (kh == 0) ? hid * w2v : 0.f;
#pragma unroll
        for (int s = 1; s < 64; s <<= 1) pr += __shfl_xor(pr, s, 64);
        if (lane == 0) out[b] = 1.f / (1.f + expf(-(pr + b2v)));
    }
}

// ---------------------------------------------------------------------------
extern "C" void kernel_launch(void* const* d_in, const int* in_sizes, int n_in,
                              void* d_out, int out_size, void* d_ws, size_t ws_size,
                              hipStream_t stream)
{
    const float* inputs = (const float*)d_in[0];
    const float* K      = (const float*)d_in[1];
    const float* R      = (const float*)d_in[2];
    const float* bias   = (const float*)d_in[3];
    const float* sinit  = (const float*)d_in[4];
    const float* w1     = (const float*)d_in[5];
    const float* b1     = (const float*)d_in[6];
    const float* w2     = (const float*)d_in[7];
    const float* b2     = (const float*)d_in[8];
    float* out = (float*)d_out;

    int*            winner = (int*)d_ws;                            // 1.0 MB
    float*          table  = (float*)((char*)d_ws + (1 << 20));     // 128 KB
    unsigned short* ids_t  = (unsigned short*)((char*)d_ws + (2 << 20)); // 4 MB

    extract_ids <<<dim3(256), dim3(1024), 0, stream>>>((const float4*)inputs, ids_t);
    find_winners<<<dim3(T_),  dim3(1024), 0, stream>>>(ids_t, winner);
    run_chains  <<<dim3(NIDS / 2), dim3(64), 0, stream>>>(inputs, K, R, bias, sinit, winner, table);
    finalize    <<<dim3(B_ / 32), dim3(256), 0, stream>>>(inputs, K, R, bias, table, w1, b1, w2, b2, out);
}